// Round 2
// baseline (888.264 us; speedup 1.0000x reference)
//
#include <hip/hip_runtime.h>

#define N_NODES 100000
#define N_EDGES 3200000
#define F_IN 256
#define CH 16
#define FCN 64

// ---------------- Kernel A: h = x @ w_gcn   [N,256] x [256,16] -> [N,16]
// Thread = (row, channel); 16 rows per block of 256 threads.
// wT staged in LDS padded to kill bank conflicts; x read as float4
// (16 lanes share a row -> coalesced broadcast fetch).
__global__ __launch_bounds__(256) void k_transform(const float* __restrict__ x,
                                                   const float* __restrict__ w,   // [256][16]
                                                   float* __restrict__ h) {
    __shared__ float wlds[CH][F_IN + 4];   // transposed, padded (+4 floats)
    int tid = threadIdx.x;
    for (int i = tid; i < F_IN * CH; i += 256) {
        int k = i >> 4, c = i & 15;
        wlds[c][k] = w[i];
    }
    __syncthreads();
    int c = tid & 15;
    int r = tid >> 4;
    int row = blockIdx.x * 16 + r;
    if (row >= N_NODES) return;
    const float4* xr = reinterpret_cast<const float4*>(x + (size_t)row * F_IN);
    const float4* wr = reinterpret_cast<const float4*>(&wlds[c][0]);  // c*1040B, 16B aligned
    float acc = 0.f;
    #pragma unroll 8
    for (int k4 = 0; k4 < F_IN / 4; ++k4) {
        float4 xv = xr[k4];
        float4 wv = wr[k4];
        acc = fmaf(xv.x, wv.x, acc);
        acc = fmaf(xv.y, wv.y, acc);
        acc = fmaf(xv.z, wv.z, acc);
        acc = fmaf(xv.w, wv.w, acc);
    }
    h[(size_t)row * CH + c] = acc;
}

// ---------------- Kernel B: edge gather + scale + scatter-add (atomics)
// 4 lanes per edge: lane group g handles channels 4g..4g+3.
// A wave gathers 16 edges' full 64B h-rows per load instruction.
__global__ __launch_bounds__(256) void k_scatter(const int* __restrict__ ei,     // [2][E]
                                                 const float* __restrict__ ew,   // [E]
                                                 const float* __restrict__ h,    // [N][16]
                                                 float* __restrict__ agg) {      // [N][16]
    long long t = (long long)blockIdx.x * 256 + threadIdx.x;
    int e = (int)(t >> 2);
    int g = (int)(t & 3);
    if (e >= N_EDGES) return;
    int src = ei[e];
    int dst = ei[N_EDGES + e];
    float w = ew[e];
    float4 hv = reinterpret_cast<const float4*>(h)[src * 4 + g];
    float* ap = agg + (size_t)dst * CH + g * 4;
    atomicAdd(ap + 0, hv.x * w);
    atomicAdd(ap + 1, hv.y * w);
    atomicAdd(ap + 2, hv.z * w);
    atomicAdd(ap + 3, hv.w * w);
}

// ---------------- Kernel C: per-node head: relu(agg) -> fc(64)+relu -> fc(1)
// One wave per node; lane = output channel of fc0; shuffle-reduce for fc1.
__global__ __launch_bounds__(256) void k_head(const float* __restrict__ agg,  // [N][16]
                                              const float* __restrict__ w0,   // [16][64]
                                              const float* __restrict__ b0,   // [64]
                                              const float* __restrict__ w1,   // [64]
                                              const float* __restrict__ b1,   // [1]
                                              float* __restrict__ out) {      // [N]
    __shared__ float w0s[CH * FCN];
    __shared__ float w1s[FCN];
    int tid = threadIdx.x;
    for (int i = tid; i < CH * FCN; i += 256) w0s[i] = w0[i];
    if (tid < FCN) w1s[tid] = w1[tid];
    __syncthreads();
    int lane = tid & 63;
    int wv   = tid >> 6;
    int node = blockIdx.x * 4 + wv;
    if (node >= N_NODES) return;
    const float* an = agg + (size_t)node * CH;
    float o1 = b0[lane];
    #pragma unroll
    for (int k = 0; k < CH; ++k) {
        float a = fmaxf(an[k], 0.f);               // relu(gcn_out) — broadcast load
        o1 = fmaf(a, w0s[k * FCN + lane], o1);     // lanes read consecutive -> 2-way banks (free)
    }
    o1 = fmaxf(o1, 0.f);
    float y = o1 * w1s[lane];
    #pragma unroll
    for (int off = 32; off > 0; off >>= 1) y += __shfl_xor(y, off, 64);
    if (lane == 0) out[node] = y + b1[0];
}

extern "C" void kernel_launch(void* const* d_in, const int* in_sizes, int n_in,
                              void* d_out, int out_size, void* d_ws, size_t ws_size,
                              hipStream_t stream) {
    const float* x  = (const float*)d_in[0];
    const int*   ei = (const int*)  d_in[1];
    const float* ew = (const float*)d_in[2];
    const float* wg = (const float*)d_in[3];
    const float* w0 = (const float*)d_in[4];
    const float* b0 = (const float*)d_in[5];
    const float* w1 = (const float*)d_in[6];
    const float* b1 = (const float*)d_in[7];
    float* out = (float*)d_out;

    float* h   = (float*)d_ws;                         // [N][16] = 6.4 MB
    float* agg = h + (size_t)N_NODES * CH;             // [N][16] = 6.4 MB

    hipMemsetAsync(agg, 0, (size_t)N_NODES * CH * sizeof(float), stream);

    k_transform<<<(N_NODES + 15) / 16, 256, 0, stream>>>(x, wg, h);

    long long sc_threads = (long long)N_EDGES * 4;
    k_scatter<<<(int)((sc_threads + 255) / 256), 256, 0, stream>>>(ei, ew, h, agg);

    k_head<<<(N_NODES + 3) / 4, 256, 0, stream>>>(agg, w0, b0, w1, b1, out);
}